// Round 9
// baseline (278.694 us; speedup 1.0000x reference)
//
#include <hip/hip_runtime.h>

// HausdorffDTLoss: exact separable EDT (fg & bg) per image, then
// mean((pred-target)^2 * (pred_dt^2 + target_dt^2)).
// Envelope identity: g[i] = min_j f[j]+(i-j)^2 = i^2 + min_j (h[j]-2ij),
// h[j]=f[j]+j^2, reassociated so the i-vector is immediates. All intermediates
// are integers <= 65282 -> u16 storage, fp32 math exact (R1-R8: absmax 0.0).
//
// R9 vs R8 (262us): VGPR_Count=16 persisted through launch-bounds changes ->
// the degenerate allocation tracks LIVE ACCUMULATOR COUNT, not occupancy
// hints. R7's unrolled 2-round envelope (32 live accs) and xloss's
// accA[16]+accB[16] made the compiler AGPR/restructure the accs (~2.2x VALU
// inflation at VALUBusy 90%). Fix: never exceed ~16 live accs --
//  - zy: r-loop forced unroll(disable) -> one acc[16] set live (R6 shape,
//    VGPR 28).
//  - xloss: stage A AND B into two LDS buffers (33.8KB, one barrier), then
//    two non-unrolled i-rounds of acc[8]+fA[8] (max ~24 live).

constexpr int BIGI = 49153;      // 3*128^2+1, matches reference BIG exactly
constexpr int NVOX = 4194304;    // voxels per tensor (2 samples x 128^3)
constexpr int STZ  = 129;        // zy dword row stride: 129%32=1 -> 2-way max (free)
constexpr int STX  = 65;         // xloss dword row stride: same property

__global__ void zero_kernel(float* out, int* flags) {
    out[0] = 0.0f;
    flags[0] = 0; flags[1] = 0; flags[2] = 0; flags[3] = 0;
}

// Fused binarize + parallel bitmask z-EDT + y-envelope for one (b,x) slab of
// one image, one polarity. 512 thr, 35.8KB LDS, 4 blocks/CU.
__global__ __launch_bounds__(512) void zy_kernel(const float* __restrict__ pred,
                                                 const float* __restrict__ tgt,
                                                 unsigned short* __restrict__ ws,
                                                 int* __restrict__ flags) {
    __shared__ unsigned int hz[65 * STZ];          // packed u16 pairs: (y-pair, z)
    __shared__ unsigned long long bm[256];         // site bitmasks: [y][z-half]
    const int t   = blockIdx.x;
    const int pol = t & 1;                         // 0: fg EDT (sites=~fg), 1: bg
    const int img = (t >> 1) & 1;
    const int s   = t >> 2;                        // 0..255: b(2) x x(128)
    const int b   = s >> 7;
    const int x   = s & 127;
    const int sb  = (b * 128 + x) * 16384;         // + y*128 + z
    const int tid = threadIdx.x;
    const float* im = img ? tgt : pred;

    // ---- stage: coalesced read -> per-wave ballot -> site bitmasks ----
    bool anyfg = false;
#pragma unroll
    for (int k = 0; k < 32; ++k) {
        int l = tid + k * 512;
        float v = im[sb + l];
        bool fg = v > 0.5f;
        anyfg |= fg;
        bool site = pol ? fg : !fg;
        unsigned long long bal = __ballot(site);
        if ((tid & 63) == 0) bm[l >> 6] = bal;     // l>>6 uniform per wave
    }
    if (!pol && __ballot(anyfg) != 0ULL && (tid & 63) == 0)
        atomicOr(flags + img * 2 + b, 1);
    __syncthreads();

    // ---- parallel z-EDT: per-voxel nearest-site distance from the masks ----
    unsigned short* hu = (unsigned short*)hz;
    const int z = tid & 127;                       // fixed per thread, uniform/wave
#pragma unroll
    for (int k = 0; k < 32; ++k) {
        int y = (tid >> 7) + k * 4;
        unsigned long long m0 = bm[2 * y], m1 = bm[2 * y + 1];
        int d;
        if (z < 64) {
            unsigned long long lm = m0 << (63 - z);
            unsigned long long rm = m0 >> z;
            int dfwd = lm ? __builtin_clzll(lm) : 999;
            int db0  = rm ? __builtin_ctzll(rm) : 999;
            int db1  = (m1 ? __builtin_ctzll(m1) : 999) + (64 - z);
            d = min(dfwd, min(db0, db1));
        } else {
            int zz = z - 64;
            unsigned long long lm = m1 << (63 - zz);
            unsigned long long rm = m1 >> zz;
            int df1 = lm ? __builtin_clzll(lm) : 999;
            int df0 = (m0 ? __builtin_clzll(m0) : 999) + zz + 1;
            int dbw = rm ? __builtin_ctzll(rm) : 999;
            d = min(min(df1, df0), dbw);
        }
        int f = (d <= 127) ? d * d : BIGI;         // empty line -> BIG (exact)
        hu[((y >> 1) * STZ) * 2 + (y & 1) + 2 * z] = (unsigned short)(f + y * y);
    }
    __syncthreads();

    // ---- y-envelope: c = z column, 4 groups, two SEQUENTIAL i-rounds ----
    unsigned short* outv = ws + (size_t)(img * 2 + pol) * NVOX;
    const int c = tid & 127;
#pragma clang loop unroll(disable)
    for (int r = 0; r < 2; ++r) {                  // one acc[16] set live at a time
        const int i0 = (tid >> 7) * 16 + r * 64;
        const float i0f = (float)i0;
        float acc[16];
#pragma unroll
        for (int k = 0; k < 16; ++k) acc[k] = 3.0e38f;
        const unsigned int* p = hz + c;
        unsigned int vc = p[0];
        float jm2 = 0.0f;                          // -2*(2q)
        for (int q = 0; q < 64; ++q) {
            unsigned int vn = p[(q + 1) * STZ];    // 1-pair prefetch (row 64 slack)
            float h0 = (float)(vc & 0xffffu);      // y = 2q
            float h1 = (float)(vc >> 16);          // y = 2q+1
            float jb  = jm2 - 2.0f;
            float hp0 = fmaf(jm2, i0f, h0);
            float hp1 = fmaf(jb,  i0f, h1);
#pragma unroll
            for (int k = 0; k < 16; ++k)
                acc[k] = fminf(acc[k], fminf(fmaf(jm2, (float)k, hp0),
                                             fmaf(jb,  (float)k, hp1)));
            jm2 -= 4.0f;
            vc = vn;
        }
#pragma unroll
        for (int k = 0; k < 16; ++k) {             // gy = acc + y^2 <= 49153: u16
            float iif = i0f + (float)k;
            outv[sb + (i0 + k) * 128 + c] = (unsigned short)(unsigned int)fmaf(iif, iif, acc[k]);
        }
    }
}

// X-envelope for A and B + fused loss partial. Tile: 64 (y,z) columns x 128 x
// of one sample of one image. 512 thr, 33.8KB LDS (A and B staged together),
// two sequential i-rounds of acc[8]+fA[8] -> max ~24 live floats.
__global__ __launch_bounds__(512) void xloss_kernel(const float* __restrict__ pred,
                                                    const float* __restrict__ tgt,
                                                    const unsigned short* __restrict__ ws,
                                                    const int* __restrict__ flags,
                                                    float* __restrict__ out) {
    __shared__ unsigned int hxA[65 * STX];
    __shared__ unsigned int hxB[65 * STX];
    __shared__ float red[8];
    const int t    = blockIdx.x;
    const int img  = t & 1;                    // adjacent blocks share pred/tgt chunk
    const int b    = (t >> 1) & 1;
    const int q0   = (t >> 2) * 64;
    const int base = b * 2097152 + q0;         // + x*16384 + c
    const int tid  = threadIdx.x;
    const int c    = tid & 63;
    const unsigned short* A16 = ws + (size_t)(img * 2) * NVOX;
    const unsigned short* B16 = A16 + NVOX;
    unsigned short* huA = (unsigned short*)hxA;
    unsigned short* huB = (unsigned short*)hxB;

    // ---- stage A and B (independent, one barrier) ----
#pragma unroll
    for (int k = 0; k < 16; ++k) {
        int l = tid + k * 512;
        int cc = l & 63, j = l >> 6;
        unsigned int va = A16[base + j * 16384 + cc];
        unsigned int vb = B16[base + j * 16384 + cc];
        int li = ((j >> 1) * STX + cc) * 2 + (j & 1);
        huA[li] = (unsigned short)(va + j * j);    // h = f + j^2 <= 65282
        huB[li] = (unsigned short)(vb + j * j);
    }
    __syncthreads();

    float s = 0.0f;
#pragma clang loop unroll(disable)
    for (int r = 0; r < 2; ++r) {                  // LDS read-only: no more barriers
        const int i0 = (tid >> 6) * 8 + r * 64;
        const float i0f = (float)i0;
        float acc[8], fA[8];

        // envelope A -> sqrt held in fA[8]
#pragma unroll
        for (int k = 0; k < 8; ++k) acc[k] = 3.0e38f;
        {
            const unsigned int* p = hxA + c;
            unsigned int vc = p[0];
            float jm2 = 0.0f;
            for (int q = 0; q < 64; ++q) {
                unsigned int vn = p[(q + 1) * STX];
                float h0 = (float)(vc & 0xffffu);
                float h1 = (float)(vc >> 16);
                float jb  = jm2 - 2.0f;
                float hp0 = fmaf(jm2, i0f, h0);
                float hp1 = fmaf(jb,  i0f, h1);
#pragma unroll
                for (int k = 0; k < 8; ++k)
                    acc[k] = fminf(acc[k], fminf(fmaf(jm2, (float)k, hp0),
                                                 fmaf(jb,  (float)k, hp1)));
                jm2 -= 4.0f;
                vc = vn;
            }
        }
#pragma unroll
        for (int k = 0; k < 8; ++k) {
            float iif = i0f + (float)k;
            fA[k] = sqrtf(fmaf(iif, iif, acc[k]));
        }

        // envelope B -> combine into loss partial
#pragma unroll
        for (int k = 0; k < 8; ++k) acc[k] = 3.0e38f;
        {
            const unsigned int* p = hxB + c;
            unsigned int vc = p[0];
            float jm2 = 0.0f;
            for (int q = 0; q < 64; ++q) {
                unsigned int vn = p[(q + 1) * STX];
                float h0 = (float)(vc & 0xffffu);
                float h1 = (float)(vc >> 16);
                float jb  = jm2 - 2.0f;
                float hp0 = fmaf(jm2, i0f, h0);
                float hp1 = fmaf(jb,  i0f, h1);
#pragma unroll
                for (int k = 0; k < 8; ++k)
                    acc[k] = fminf(acc[k], fminf(fmaf(jm2, (float)k, hp0),
                                                 fmaf(jb,  (float)k, hp1)));
                jm2 -= 4.0f;
                vc = vn;
            }
        }
#pragma unroll
        for (int k = 0; k < 8; ++k) {
            float iif = i0f + (float)k;
            float fld = fA[k] + sqrtf(fmaf(iif, iif, acc[k]));
            int v = base + (i0 + k) * 16384 + c;   // coalesced across c per k
            float d = pred[v] - tgt[v];
            s += d * d * fld * fld;
        }
    }

    if (!flags[img * 2 + b]) s = 0.0f;
#pragma unroll
    for (int off = 32; off > 0; off >>= 1) s += __shfl_down(s, off);
    if ((tid & 63) == 0) red[tid >> 6] = s;
    __syncthreads();
    if (tid == 0) {
        float tot = 0.0f;
#pragma unroll
        for (int w = 0; w < 8; ++w) tot += red[w];
        atomicAdd(out, tot * (1.0f / 4194304.0f));
    }
}

extern "C" void kernel_launch(void* const* d_in, const int* in_sizes, int n_in,
                              void* d_out, int out_size, void* d_ws, size_t ws_size,
                              hipStream_t stream) {
    const float* pred = (const float*)d_in[0];
    const float* tgt  = (const float*)d_in[1];
    float* out = (float*)d_out;
    unsigned short* ws16 = (unsigned short*)d_ws;  // 4 u16 volumes = 33.6 MB
    int* flags = (int*)(ws16 + 4 * (size_t)NVOX);  // [img0_b0, img0_b1, img1_b0, img1_b1]

    zero_kernel<<<1, 1, 0, stream>>>(out, flags);
    zy_kernel<<<dim3(1024), 512, 0, stream>>>(pred, tgt, ws16, flags);
    xloss_kernel<<<dim3(1024), 512, 0, stream>>>(pred, tgt, ws16, flags, out);
}

// Round 10
// 248.259 us; speedup vs baseline: 1.1226x; 1.1226x over previous
//
#include <hip/hip_runtime.h>

// HausdorffDTLoss: exact separable EDT (fg & bg) per image, then
// mean((pred-target)^2 * (pred_dt^2 + target_dt^2)).
// Envelope identity: g[i] = min_j f[j]+(i-j)^2 = i^2 + min_j (h[j]-2ij),
// h[j]=f[j]+j^2. All intermediates are integers <= 65282 -> u16 storage,
// fp32 math exact (R1-R9: absmax 0.0).
//
// R10 vs R9 (278us; VGPR_Count=16 degenerate allocation survived launch
// bounds AND unroll/live-range changes): new theory -- the unrolled inner
// `fmaf(jm2, (float)k, hp)` needs fp32 LITERALS (k=3,5,6,7,...) which VOP3
// v_fma_f32 cannot encode; under the squeezed budget the compiler
// rematerializes constants per-iteration and AGPR-shuffles the accs (~1.8x
// VALU inflation). Fix: additive-chain candidates -- c0 += jm2 between k's --
// zero literals in the hot loop, every operand a VGPR, exact integer math
// unchanged. xloss reverted to the R8 single-buffer structure (R9 regressed).

constexpr int BIGI = 49153;      // 3*128^2+1, matches reference BIG exactly
constexpr int NVOX = 4194304;    // voxels per tensor (2 samples x 128^3)
constexpr int STZ  = 129;        // zy dword row stride: 129%32=1 -> 2-way max (free)
constexpr int STX  = 65;         // xloss dword row stride: same property

__global__ void zero_kernel(float* out, int* flags) {
    out[0] = 0.0f;
    flags[0] = 0; flags[1] = 0; flags[2] = 0; flags[3] = 0;
}

// Fused binarize + parallel bitmask z-EDT + y-envelope for one (b,x) slab of
// one image, one polarity. 512 thr, 35.8KB LDS, 4 blocks/CU.
__global__ __launch_bounds__(512) void zy_kernel(const float* __restrict__ pred,
                                                 const float* __restrict__ tgt,
                                                 unsigned short* __restrict__ ws,
                                                 int* __restrict__ flags) {
    __shared__ unsigned int hz[65 * STZ];          // packed u16 pairs: (y-pair, z)
    __shared__ unsigned long long bm[256];         // site bitmasks: [y][z-half]
    const int t   = blockIdx.x;
    const int pol = t & 1;                         // 0: fg EDT (sites=~fg), 1: bg
    const int img = (t >> 1) & 1;
    const int s   = t >> 2;                        // 0..255: b(2) x x(128)
    const int b   = s >> 7;
    const int x   = s & 127;
    const int sb  = (b * 128 + x) * 16384;         // + y*128 + z
    const int tid = threadIdx.x;
    const float* im = img ? tgt : pred;

    // ---- stage: coalesced read -> per-wave ballot -> site bitmasks ----
    bool anyfg = false;
#pragma unroll
    for (int k = 0; k < 32; ++k) {
        int l = tid + k * 512;
        float v = im[sb + l];
        bool fg = v > 0.5f;
        anyfg |= fg;
        bool site = pol ? fg : !fg;
        unsigned long long bal = __ballot(site);
        if ((tid & 63) == 0) bm[l >> 6] = bal;     // l>>6 uniform per wave
    }
    if (!pol && __ballot(anyfg) != 0ULL && (tid & 63) == 0)
        atomicOr(flags + img * 2 + b, 1);
    __syncthreads();

    // ---- parallel z-EDT: per-voxel nearest-site distance from the masks ----
    unsigned short* hu = (unsigned short*)hz;
    const int z = tid & 127;                       // fixed per thread, uniform/wave
#pragma unroll
    for (int k = 0; k < 32; ++k) {
        int y = (tid >> 7) + k * 4;
        unsigned long long m0 = bm[2 * y], m1 = bm[2 * y + 1];
        int d;
        if (z < 64) {
            unsigned long long lm = m0 << (63 - z);
            unsigned long long rm = m0 >> z;
            int dfwd = lm ? __builtin_clzll(lm) : 999;
            int db0  = rm ? __builtin_ctzll(rm) : 999;
            int db1  = (m1 ? __builtin_ctzll(m1) : 999) + (64 - z);
            d = min(dfwd, min(db0, db1));
        } else {
            int zz = z - 64;
            unsigned long long lm = m1 << (63 - zz);
            unsigned long long rm = m1 >> zz;
            int df1 = lm ? __builtin_clzll(lm) : 999;
            int df0 = (m0 ? __builtin_clzll(m0) : 999) + zz + 1;
            int dbw = rm ? __builtin_ctzll(rm) : 999;
            d = min(min(df1, df0), dbw);
        }
        int f = (d <= 127) ? d * d : BIGI;         // empty line -> BIG (exact)
        hu[((y >> 1) * STZ) * 2 + (y & 1) + 2 * z] = (unsigned short)(f + y * y);
    }
    __syncthreads();

    // ---- y-envelope: c = z column, 4 groups, two SEQUENTIAL i-rounds ----
    unsigned short* outv = ws + (size_t)(img * 2 + pol) * NVOX + sb;
    const int c = tid & 127;
#pragma clang loop unroll(disable)
    for (int r = 0; r < 2; ++r) {                  // one acc[16] set live at a time
        const int i0 = (tid >> 7) * 16 + r * 64;
        const float i0f = (float)i0;
        float acc[16];
#pragma unroll
        for (int k = 0; k < 16; ++k) acc[k] = 3.0e38f;
        const unsigned int* p = hz + c;
        unsigned int vc = p[0];
        float jm2 = 0.0f;                          // -2*(2q)
        for (int q = 0; q < 64; ++q) {
            unsigned int vn = p[(q + 1) * STZ];    // 1-pair prefetch (row 64 slack)
            float h0 = (float)(vc & 0xffffu);      // y = 2q
            float h1 = (float)(vc >> 16);          // y = 2q+1
            float jb = jm2 - 2.0f;
            float c0 = fmaf(jm2, i0f, h0);         // candidate at i = i0
            float c1 = fmaf(jb,  i0f, h1);
#pragma unroll
            for (int k = 0; k < 16; ++k) {         // chain: no literals in loop
                acc[k] = fminf(acc[k], fminf(c0, c1));
                c0 += jm2; c1 += jb;               // exact: integers < 2^17
            }
            jm2 -= 4.0f;
            vc = vn;
        }
#pragma unroll
        for (int k = 0; k < 16; ++k) {             // gy = acc + y^2 <= 49153: u16
            float iif = i0f + (float)k;
            outv[(i0 + k) * 128 + c] = (unsigned short)(unsigned int)fmaf(iif, iif, acc[k]);
        }
    }
}

// X-envelope for A and B + fused loss partial (R8 structure, chain inner).
// Tile: 64 (y,z) columns x 128 x of one sample of one image. 512 thr, 16.9KB LDS.
__global__ __launch_bounds__(512) void xloss_kernel(const float* __restrict__ pred,
                                                    const float* __restrict__ tgt,
                                                    const unsigned short* __restrict__ ws,
                                                    const int* __restrict__ flags,
                                                    float* __restrict__ out) {
    __shared__ unsigned int hx[65 * STX];
    __shared__ float red[8];
    const int t    = blockIdx.x;
    const int img  = t & 1;                    // adjacent blocks share pred/tgt chunk
    const int b    = (t >> 1) & 1;
    const int q0   = (t >> 2) * 64;
    const int base = b * 2097152 + q0;         // + x*16384 + c
    const int tid  = threadIdx.x;
    const int c    = tid & 63;
    const int i0   = (tid >> 6) * 16;
    const float i0f = (float)i0;
    unsigned short* hu = (unsigned short*)hx;
    const unsigned short* A16 = ws + (size_t)(img * 2) * NVOX;
    const unsigned short* B16 = A16 + NVOX;
    float accA[16], accB[16];

    // ---- stage + envelope A ----
#pragma unroll
    for (int k = 0; k < 16; ++k) {
        int l = tid + k * 512;
        int cc = l & 63, j = l >> 6;
        unsigned int v = A16[base + j * 16384 + cc];
        hu[((j >> 1) * STX + cc) * 2 + (j & 1)] = (unsigned short)(v + j * j); // <=65282
    }
    __syncthreads();
    {
#pragma unroll
        for (int k = 0; k < 16; ++k) accA[k] = 3.0e38f;
        const unsigned int* p = hx + c;
        unsigned int vc = p[0];
        float jm2 = 0.0f;
        for (int q = 0; q < 64; ++q) {
            unsigned int vn = p[(q + 1) * STX];
            float h0 = (float)(vc & 0xffffu);
            float h1 = (float)(vc >> 16);
            float jb = jm2 - 2.0f;
            float c0 = fmaf(jm2, i0f, h0);
            float c1 = fmaf(jb,  i0f, h1);
#pragma unroll
            for (int k = 0; k < 16; ++k) {
                accA[k] = fminf(accA[k], fminf(c0, c1));
                c0 += jm2; c1 += jb;
            }
            jm2 -= 4.0f;
            vc = vn;
        }
    }
    __syncthreads();

    // ---- stage + envelope B ----
#pragma unroll
    for (int k = 0; k < 16; ++k) {
        int l = tid + k * 512;
        int cc = l & 63, j = l >> 6;
        unsigned int v = B16[base + j * 16384 + cc];
        hu[((j >> 1) * STX + cc) * 2 + (j & 1)] = (unsigned short)(v + j * j);
    }
    __syncthreads();
    {
#pragma unroll
        for (int k = 0; k < 16; ++k) accB[k] = 3.0e38f;
        const unsigned int* p = hx + c;
        unsigned int vc = p[0];
        float jm2 = 0.0f;
        for (int q = 0; q < 64; ++q) {
            unsigned int vn = p[(q + 1) * STX];
            float h0 = (float)(vc & 0xffffu);
            float h1 = (float)(vc >> 16);
            float jb = jm2 - 2.0f;
            float c0 = fmaf(jm2, i0f, h0);
            float c1 = fmaf(jb,  i0f, h1);
#pragma unroll
            for (int k = 0; k < 16; ++k) {
                accB[k] = fminf(accB[k], fminf(c0, c1));
                c0 += jm2; c1 += jb;
            }
            jm2 -= 4.0f;
            vc = vn;
        }
    }

    // ---- loss partial: (p-t)^2 * (sqrt(gA)+sqrt(gB))^2 * guard ----
    float s = 0.0f;
#pragma unroll
    for (int k = 0; k < 16; ++k) {
        float iif = i0f + (float)k;
        float gA = fmaf(iif, iif, accA[k]);
        float gB = fmaf(iif, iif, accB[k]);
        int v = base + (i0 + k) * 16384 + c;     // coalesced across c per k
        float d = pred[v] - tgt[v];
        float fld = sqrtf(gA) + sqrtf(gB);
        s += d * d * fld * fld;
    }
    if (!flags[img * 2 + b]) s = 0.0f;
#pragma unroll
    for (int off = 32; off > 0; off >>= 1) s += __shfl_down(s, off);
    if ((tid & 63) == 0) red[tid >> 6] = s;
    __syncthreads();
    if (tid == 0) {
        float tot = 0.0f;
#pragma unroll
        for (int w = 0; w < 8; ++w) tot += red[w];
        atomicAdd(out, tot * (1.0f / 4194304.0f));
    }
}

extern "C" void kernel_launch(void* const* d_in, const int* in_sizes, int n_in,
                              void* d_out, int out_size, void* d_ws, size_t ws_size,
                              hipStream_t stream) {
    const float* pred = (const float*)d_in[0];
    const float* tgt  = (const float*)d_in[1];
    float* out = (float*)d_out;
    unsigned short* ws16 = (unsigned short*)d_ws;  // 4 u16 volumes = 33.6 MB
    int* flags = (int*)(ws16 + 4 * (size_t)NVOX);  // [img0_b0, img0_b1, img1_b0, img1_b1]

    zero_kernel<<<1, 1, 0, stream>>>(out, flags);
    zy_kernel<<<dim3(1024), 512, 0, stream>>>(pred, tgt, ws16, flags);
    xloss_kernel<<<dim3(1024), 512, 0, stream>>>(pred, tgt, ws16, flags, out);
}